// Round 4
// baseline (313.075 us; speedup 1.0000x reference)
//
#include <hip/hip_runtime.h>
#include <math.h>

#define BATCH   32768
#define NCLS    2048
#define BLOCK   64                  // one wave per block: ballot, no LDS, no barriers
#define NBLOCKS (BATCH / BLOCK)     // 512

// One thread per row.
//   t != 0 : loss = log(e^{x0} + e^{xt}) - xt = log1p(e^{x0 - xt})   (2 scattered loads)
//   t == 0 : loss = log(sum_j e^{xj}) - x0                            (~16 rows of 32768)
// Finalize fused via last-block-done: device-scope atomics + threadfence
// (HW-verified coherent cross-XCD, m20); no dispatch-order assumption.
__global__ __launch_bounds__(BLOCK) void mpl_fused(const float* __restrict__ x,
                                                   const int* __restrict__ tgt,
                                                   float* __restrict__ out,
                                                   float* __restrict__ acc,
                                                   unsigned int* __restrict__ done) {
    const int row = blockIdx.x * BLOCK + threadIdx.x;   // BATCH % BLOCK == 0

    // x0's address is t-independent: issues in parallel with the tgt load.
    const float x0 = x[(size_t)row * NCLS];
    const int t = tgt[row];
    const bool zero = (t == 0);

    // Unconditional xt load: for t==0 it aliases x0 (harmless, L1-hot).
    // No branch => no exec-mask churn; load issues as soon as t lands.
    const float xt = x[(size_t)row * NCLS + t];
    const float cheap = log1pf(expf(x0 - xt));
    float li = zero ? 0.0f : cheap;

    // wave-reduce the cheap-path losses (lane 0 ends with the wave sum)
    #pragma unroll
    for (int o = 32; o > 0; o >>= 1) li += __shfl_down(li, o, 64);

    // expensive path: rare t == 0 rows, found via ballot
    unsigned long long m = __ballot(zero);
    while (m) {
        const int b = __ffsll((unsigned long long)m) - 1;
        m &= m - 1;
        const int zr = blockIdx.x * BLOCK + b;
        const float4* xr = (const float4*)(x + (size_t)zr * NCLS);
        float s = 0.0f;
        #pragma unroll
        for (int j = threadIdx.x; j < NCLS / 4; j += BLOCK) {
            const float4 v = xr[j];
            s += expf(v.x) + expf(v.y) + expf(v.z) + expf(v.w);
        }
        #pragma unroll
        for (int o = 32; o > 0; o >>= 1) s += __shfl_down(s, o, 64);
        if (threadIdx.x == 0) {
            const float zx0 = x[(size_t)zr * NCLS];   // L1-hot after the row sweep
            li += logf(s) - zx0;                      // li holds wave sum on lane 0
        }
    }

    if (threadIdx.x == 0) {
        atomicAdd(acc, li);                 // device-scope, cross-XCD coherent
        __threadfence();                    // release our add before taking a ticket
        const unsigned int ticket = atomicAdd(done, 1u);
        if (ticket == NBLOCKS - 1) {
            __threadfence();                // acquire all other blocks' adds
            const float total = atomicAdd(acc, 0.0f);   // coherent read via atomic
            out[0] = total * (1.0f / (float)BATCH);
        }
    }
}

extern "C" void kernel_launch(void* const* d_in, const int* in_sizes, int n_in,
                              void* d_out, int out_size, void* d_ws, size_t ws_size,
                              hipStream_t stream) {
    const float* x   = (const float*)d_in[0];
    const int*   tgt = (const int*)d_in[1];
    float* out = (float*)d_out;
    float*        acc  = (float*)d_ws;
    unsigned int* done = (unsigned int*)d_ws + 1;

    hipMemsetAsync(d_ws, 0, 2 * sizeof(float), stream);   // acc = 0, done = 0
    mpl_fused<<<NBLOCKS, BLOCK, 0, stream>>>(x, tgt, out, acc, done);
}

// Round 7
// 307.441 us; speedup vs baseline: 1.0183x; 1.0183x over previous
//
#include <hip/hip_runtime.h>
#include <math.h>

#define BATCH   32768
#define NCLS    2048
#define BLOCK   64                  // one wave per block: ballot, no LDS, no barriers
#define NBLOCKS (BATCH / BLOCK)     // 512

// One thread per row.
//   t != 0 : loss = log(e^{x0} + e^{xt}) - xt = log1p(e^{x0 - xt})   (2 scattered loads)
//   t == 0 : loss = log(sum_j e^{xj}) - x0                            (~16 rows of 32768)
//
// NO WORKSPACE USE: round-4 rocprof showed the timed region dominated by the
// harness re-poisoning the 1 GiB workspace (2× fillBufferAligned @ ~162 µs,
// WRITE_SIZE = 1 GiB each) because earlier versions mutated d_ws. Each block
// adds its pre-scaled partial straight into out[0] (4-byte memset at launch).
__global__ __launch_bounds__(BLOCK) void mpl_fused(const float* __restrict__ x,
                                                   const int* __restrict__ tgt,
                                                   float* __restrict__ out) {
    const int row = blockIdx.x * BLOCK + threadIdx.x;   // BATCH % BLOCK == 0

    // x0's address is t-independent: issues in parallel with the tgt load.
    const float x0 = x[(size_t)row * NCLS];
    const int t = tgt[row];
    const bool zero = (t == 0);

    // Unconditional xt load: for t==0 it aliases x0 (harmless, L1-hot).
    const float xt = x[(size_t)row * NCLS + t];
    const float cheap = log1pf(expf(x0 - xt));
    float li = zero ? 0.0f : cheap;

    // wave-reduce the cheap-path losses (lane 0 ends with the wave sum)
    #pragma unroll
    for (int o = 32; o > 0; o >>= 1) li += __shfl_down(li, o, 64);

    // expensive path: rare t == 0 rows, found via ballot
    unsigned long long m = __ballot(zero);
    while (m) {
        const int b = __ffsll((unsigned long long)m) - 1;
        m &= m - 1;
        const int zr = blockIdx.x * BLOCK + b;
        const float4* xr = (const float4*)(x + (size_t)zr * NCLS);
        float s = 0.0f;
        #pragma unroll
        for (int j = threadIdx.x; j < NCLS / 4; j += BLOCK) {
            const float4 v = xr[j];
            s += expf(v.x) + expf(v.y) + expf(v.z) + expf(v.w);
        }
        #pragma unroll
        for (int o = 32; o > 0; o >>= 1) s += __shfl_down(s, o, 64);
        if (threadIdx.x == 0) {
            const float zx0 = x[(size_t)zr * NCLS];   // L1-hot after the row sweep
            li += logf(s) - zx0;                      // li holds wave sum on lane 0
        }
    }

    // Pre-scaled add directly into the 4-byte output — no workspace state.
    if (threadIdx.x == 0) atomicAdd(out, li * (1.0f / (float)BATCH));
}

extern "C" void kernel_launch(void* const* d_in, const int* in_sizes, int n_in,
                              void* d_out, int out_size, void* d_ws, size_t ws_size,
                              hipStream_t stream) {
    const float* x   = (const float*)d_in[0];
    const int*   tgt = (const int*)d_in[1];
    float* out = (float*)d_out;
    (void)d_ws; (void)ws_size;

    hipMemsetAsync(d_out, 0, sizeof(float), stream);   // out = 0 (4 bytes)
    mpl_fused<<<NBLOCKS, BLOCK, 0, stream>>>(x, tgt, out);
}